// Round 15
// baseline (741.667 us; speedup 1.0000x reference)
//
#include <hip/hip_runtime.h>
#include <hip/hip_bf16.h>
#include <cstdio>

typedef __hip_bfloat16 bf16;
typedef __attribute__((ext_vector_type(8))) short short8;   // 8 bf16 = 4 VGPR
typedef __attribute__((ext_vector_type(4))) short short4v;
typedef __attribute__((ext_vector_type(4))) float f32x4;
typedef __attribute__((ext_vector_type(2))) float f32x2;

#define NB    32
#define NK    256
#define NDIN  512
#define NPROJ 64
#define NDM   128
#define NNL   3
#define NT    63
#define NDI   256
#define NSEQ  2048            // NB*NPROJ
#define NROW  (NSEQ*NT)       // 129024
#define LDP   136             // LDS K-stride in shorts (17 * 16B)

static __device__ __forceinline__ float b2f(bf16 v){ return __bfloat162float(v); }
static __device__ __forceinline__ bf16  f2b(float v){ return __float2bfloat16(v); }
static __device__ __forceinline__ unsigned short f2bs(float v){   // RNE f32->bf16 bits
  unsigned int u = __float_as_uint(v);
  return (unsigned short)((u + 0x7FFFu + ((u >> 16) & 1u)) >> 16);
}
static __device__ __forceinline__ float bs2f(unsigned short b){   // bf16 bits -> f32
  return __uint_as_float(((unsigned int)b) << 16);
}
static __device__ __forceinline__ f32x2 lo2(f32x4 v){ f32x2 r; r.x = v.x; r.y = v.y; return r; }
static __device__ __forceinline__ f32x2 hi2(f32x4 v){ f32x2 r; r.x = v.z; r.y = v.w; return r; }
// silu via v_rcp (1 slot) instead of IEEE div (~9 slots)
static __device__ __forceinline__ float siluf(float x){
  return x * __builtin_amdgcn_rcpf(1.f + __expf(-x));
}
static __device__ __forceinline__ float softplusf(float x){
  float e = __expf(-fabsf(x));
  return fmaxf(x, 0.f) + __logf(1.f + e);
}

// ---------------------------------------------------------------------------
// 0) all-layer weight pre-transpose to K-major bf16 (one dispatch).
__global__ __launch_bounds__(256) void k_tw_all(
    const float* __restrict__ Wi, const float* __restrict__ Wo,
    const float* __restrict__ Wx,
    unsigned short* __restrict__ WiT, unsigned short* __restrict__ WoT,
    unsigned short* __restrict__ WxT)
{
  int bx = blockIdx.x;
  int l = bx / 704, r = bx - l*704;
  const float* src; unsigned short* dst; int K, srcN, nvalid, n;
  if (r < 512)      { n = r;     src = Wi + (size_t)l*128*512; dst = WiT + (size_t)l*512*128; K=128; srcN=512; nvalid=512; }
  else if (r < 640) { n = r-512; src = Wo + (size_t)l*256*128; dst = WoT + (size_t)l*128*256; K=256; srcN=128; nvalid=128; }
  else              { n = r-640; src = Wx + (size_t)l*256*40;  dst = WxT + (size_t)l*64*256;  K=256; srcN=40;  nvalid=40; }
  for (int k = threadIdx.x; k < K; k += 256) {
    float v = (n < nvalid) ? src[(size_t)k*srcN + n] : 0.f;
    dst[(size_t)n*K + k] = f2bs(v);
  }
}

// ---------------------------------------------------------------------------
// 1) hp[n][k] = x[b,k,:] . W_proj[:,p] + b_proj[p]
__global__ __launch_bounds__(64) void k_proj(const float* __restrict__ x,
                       const float* __restrict__ Wp,
                       const float* __restrict__ bp, float* __restrict__ hp)
{
  int b  = blockIdx.x >> 6;          // batch
  int kq = blockIdx.x & 63;          // covers k = kq*4 .. kq*4+3
  __shared__ float xr[4][NDIN+1];
  for (int e = threadIdx.x; e < 4*NDIN; e += 64) {
    int row = e >> 9, col = e & 511;
    xr[row][col] = x[(size_t)(b*NK + kq*4 + row)*NDIN + col];
  }
  __syncthreads();
  int p = threadIdx.x;
  float bias = bp[p];
  float a0 = bias, a1 = bias, a2 = bias, a3 = bias;
  #pragma unroll 4
  for (int d = 0; d < NDIN; ++d) {
    float w = Wp[d*NPROJ + p];
    a0 += xr[0][d]*w; a1 += xr[1][d]*w; a2 += xr[2][d]*w; a3 += xr[3][d]*w;
  }
  float* dst = hp + (size_t)(b*NPROJ + p)*NK + kq*4;
  dst[0] = a0; dst[1] = a1; dst[2] = a2; dst[3] = a3;
}

// ---------------------------------------------------------------------------
// 2) u[n,t,m] (bf16) = sum_j hp[n][t*4+j] * We[j][m] + be[m]
__global__ __launch_bounds__(256, 4) void k_embed(const float* __restrict__ hp,
                        const float* __restrict__ We,
                        const float* __restrict__ be, unsigned short* __restrict__ u)
{
  __shared__ float sWe[8][NDM];
  __shared__ float sbe[NDM];
  for (int e = threadIdx.x; e < 8*NDM; e += 256) sWe[e >> 7][e & 127] = We[e];
  if (threadIdx.x < NDM) sbe[threadIdx.x] = be[threadIdx.x];
  __syncthreads();
  int r = blockIdx.x*64 + (threadIdx.x >> 2);
  int strip = (threadIdx.x & 3) * 32;
  int n = r / NT, t = r - n*NT;
  const float* hr = hp + (size_t)n*NK + t*4;
  float h[8];
  #pragma unroll
  for (int j = 0; j < 8; ++j) h[j] = hr[j];
  float acc[32];
  #pragma unroll
  for (int c = 0; c < 32; ++c) acc[c] = sbe[strip + c];
  #pragma unroll
  for (int j = 0; j < 8; ++j)
    #pragma unroll
    for (int c = 0; c < 32; ++c)
      acc[c] += h[j] * sWe[j][strip + c];
  unsigned short* dst = u + (size_t)r*NDM + strip;
  #pragma unroll
  for (int g = 0; g < 4; ++g) {
    short8 o;
    #pragma unroll
    for (int i = 0; i < 8; ++i) o[i] = (short)f2bs(acc[g*8 + i]);
    *(short8*)&dst[g*8] = o;
  }
}

// ---------------------------------------------------------------------------
// 3) in_proj + fused rmsnorm. A staged once; loop 4 B-tiles in-kernel.
//    z output stored PRE-GATED: zb = silu(zacc).
__global__ __launch_bounds__(256) void k_inproj(
    const unsigned short* __restrict__ ub, const unsigned short* __restrict__ WT,
    unsigned short* __restrict__ xh, unsigned short* __restrict__ zb,
    const float* __restrict__ nw)
{
  __shared__ short As[64*LDP];
  __shared__ short Bs[128*LDP];
  const int tid  = threadIdx.x;
  const int r0   = blockIdx.x * 64;
  const int w    = tid >> 6;
  const int lane = tid & 63;
  const int l16  = lane & 15;
  const int quad = lane >> 4;
  const int WM   = (w >> 1) * 32;
  const int WN   = (w & 1) * 64;

  #pragma unroll
  for (int j = 0; j < 4; ++j) {
    int c = tid + j*256;
    int row = c >> 4, k8 = (c & 15) << 3;
    short8 vb = *(const short8*)&ub[(size_t)(r0+row)*128 + k8];
    float f[8];
    #pragma unroll
    for (int i = 0; i < 8; ++i) f[i] = bs2f((unsigned short)vb[i]);
    float ss = 0.f;
    #pragma unroll
    for (int i = 0; i < 8; ++i) ss += f[i]*f[i];
    #pragma unroll
    for (int m = 8; m >= 1; m >>= 1) ss += __shfl_xor(ss, m, 16);
    float sc = rsqrtf(ss*(1.f/128.f) + 1e-5f);
    const float4 nw0 = *(const float4*)&nw[k8];
    const float4 nw1 = *(const float4*)&nw[k8+4];
    short8 o;
    o[0] = (short)f2bs(f[0]*sc*nw0.x); o[1] = (short)f2bs(f[1]*sc*nw0.y);
    o[2] = (short)f2bs(f[2]*sc*nw0.z); o[3] = (short)f2bs(f[3]*sc*nw0.w);
    o[4] = (short)f2bs(f[4]*sc*nw1.x); o[5] = (short)f2bs(f[5]*sc*nw1.y);
    o[6] = (short)f2bs(f[6]*sc*nw1.z); o[7] = (short)f2bs(f[7]*sc*nw1.w);
    *(short8*)&As[row*LDP + k8] = o;
  }

  for (int ny = 0; ny < 4; ++ny) {
    if (ny) __syncthreads();
    #pragma unroll
    for (int j = 0; j < 8; ++j) {
      int c = tid + j*256;
      int n = c >> 4, k8 = (c & 15) << 3;
      *(short8*)&Bs[n*LDP + k8] =
          *(const short8*)&WT[(size_t)(ny*128 + n)*128 + k8];
    }
    __syncthreads();

    f32x4 acc[2][4] = {};
    #pragma unroll
    for (int ks = 0; ks < 4; ++ks) {
      short8 a[2], b[4];
      #pragma unroll
      for (int i = 0; i < 2; ++i)
        a[i] = *(const short8*)&As[(WM + i*16 + l16)*LDP + ks*32 + quad*8];
      #pragma unroll
      for (int j = 0; j < 4; ++j)
        b[j] = *(const short8*)&Bs[(WN + j*16 + l16)*LDP + ks*32 + quad*8];
      #pragma unroll
      for (int i = 0; i < 2; ++i)
        #pragma unroll
        for (int j = 0; j < 4; ++j)
          acc[i][j] = __builtin_amdgcn_mfma_f32_16x16x32_bf16(a[i], b[j], acc[i][j], 0, 0, 0);
    }
    #pragma unroll
    for (int i = 0; i < 2; ++i) {
      #pragma unroll
      for (int j = 0; j < 4; ++j) {
        #pragma unroll
        for (int rr = 0; rr < 4; ++rr) {
          int row = r0 + WM + i*16 + quad*4 + rr;
          int col = ny*128 + WN + j*16 + l16;
          float v = acc[i][j][rr];
          if (col < 256) xh[(size_t)row*256 + col]       = f2bs(v);
          else           zb[(size_t)row*256 + col - 256] = f2bs(siluf(v));
        }
      }
    }
  }
}

// ---------------------------------------------------------------------------
// 4) MFMA GEMM (x_proj / out_proj).
template<int MODE, int KTOT, int BN>
__global__ __launch_bounds__(256) void
k_mgemm(const void* __restrict__ Aptr, const unsigned short* __restrict__ WT,
        void* __restrict__ Cptr)
{
  constexpr int MJ = BN/32;
  __shared__ short As[64*LDP];
  __shared__ short Bs[BN*LDP];

  const int tid  = threadIdx.x;
  const int r0   = blockIdx.x * 64;
  const int w    = tid >> 6;
  const int lane = tid & 63;
  const int l16  = lane & 15;
  const int quad = lane >> 4;
  const int WM   = (w >> 1) * 32;
  const int WN   = (w & 1) * (BN/2);

  f32x4 acc[2][MJ] = {};

  for (int kc = 0; kc < KTOT; kc += 128) {
    #pragma unroll
    for (int j = 0; j < 4; ++j) {
      int c   = tid + j*256;
      int row = c >> 4, k8 = (c & 15) << 3;
      short8 v = *(const short8*)((const unsigned short*)Aptr
                                  + (size_t)(r0+row)*256 + kc + k8);
      *(short8*)&As[row*LDP + k8] = v;
    }
    #pragma unroll
    for (int j = 0; j < BN/16; ++j) {
      int c  = tid + j*256;
      int n  = c >> 4, k8 = (c & 15) << 3;
      short8 v = *(const short8*)(WT + (size_t)n*KTOT + kc + k8);
      *(short8*)&Bs[n*LDP + k8] = v;
    }
    __syncthreads();

    #pragma unroll
    for (int ks = 0; ks < 4; ++ks) {
      short8 a[2], b[MJ];
      #pragma unroll
      for (int i = 0; i < 2; ++i)
        a[i] = *(const short8*)&As[(WM + i*16 + l16)*LDP + ks*32 + quad*8];
      #pragma unroll
      for (int j = 0; j < MJ; ++j)
        b[j] = *(const short8*)&Bs[(WN + j*16 + l16)*LDP + ks*32 + quad*8];
      #pragma unroll
      for (int i = 0; i < 2; ++i)
        #pragma unroll
        for (int j = 0; j < MJ; ++j)
          acc[i][j] = __builtin_amdgcn_mfma_f32_16x16x32_bf16(a[i], b[j], acc[i][j], 0, 0, 0);
    }
    __syncthreads();
  }

  #pragma unroll
  for (int i = 0; i < 2; ++i) {
    #pragma unroll
    for (int j = 0; j < MJ; ++j) {
      #pragma unroll
      for (int rr = 0; rr < 4; ++rr) {
        int row = r0 + WM + i*16 + quad*4 + rr;
        int col = WN + j*16 + l16;
        float v = acc[i][j][rr];
        if (MODE == 1) {
          if (col < 40) ((float*)Cptr)[(size_t)row*40 + col] = v;
        } else {
          unsigned short* p = (unsigned short*)Cptr + (size_t)row*128 + col;
          *p = f2bs(bs2f(*p) + v);
        }
      }
    }
  }
}

// ---------------------------------------------------------------------------
// 5) depthwise causal conv(4) + bias + silu, IN PLACE on xh (stride 256).
__global__ __launch_bounds__(256, 8) void k_conv(bf16* __restrict__ xh,
                       const float* __restrict__ cw, const float* __restrict__ cb)
{
  int n = blockIdx.x, d = threadIdx.x;
  float w0 = cw[d*4+0], w1 = cw[d*4+1];
  float w2 = cw[d*4+2], w3 = cw[d*4+3];
  float bias = cb[d];
  float xm3 = 0.f, xm2 = 0.f, xm1 = 0.f;
  bf16* ptr = xh + (size_t)n*NT*256 + d;
  for (int t = 0; t < NT; ++t) {
    float xt = b2f(ptr[0]);
    float a  = bias + w0*xm3 + w1*xm2 + w2*xm1 + w3*xt;
    ptr[0] = f2b(siluf(a));
    ptr += 256;
    xm3 = xm2; xm2 = xm1; xm1 = xt;
  }
}

// ---------------------------------------------------------------------------
// 6) fused dt_proj + softplus + selective scan + skip + gating (z pre-silu'd).
//    W=2 (128 thr), f32x2 packed math, dt-row + u/z prefetch.
//    CHANNEL REMAP vs R13: lane owns ADJACENT channels {d, d+1},
//    d = 2*lane + 128*wave — all u/z/y traffic becomes ushort2 (4B/lane).
__global__ __launch_bounds__(128, 4) void k_scan(const float* __restrict__ dbl,
                       const bf16* __restrict__ z, bf16* __restrict__ xh,
                       const float* __restrict__ Wdt, const float* __restrict__ bdt,
                       const float* __restrict__ Alog, const float* __restrict__ Dpp)
{
  int n = blockIdx.x;
  int tid = threadIdx.x;
  int lane = tid & 63, wv = tid >> 6;
  __shared__ __align__(16) float sd[NT+1][40];    // dt(8) | B(16) | C(16); +1 pad row
  for (int i = tid; i < NT*40; i += 128)
    sd[i/40][i%40] = dbl[(size_t)n*NT*40 + i];
  if (tid < 40) sd[NT][tid] = 0.f;
  __syncthreads();

  // channels: d_j = 2*lane + 128*wv + j, j=0,1 (adjacent -> ushort2 I/O)
  const int dbase = 2*lane + 128*wv;
  float bd[2], dp2[2];
  f32x2 wdt2[2][4];
  bool chain = true;
  #pragma unroll
  for (int j = 0; j < 2; ++j) {
    int d = dbase + j;
    bd[j]  = bdt[d];
    dp2[j] = Dpp[d];
    #pragma unroll
    for (int r = 0; r < 4; ++r) {
      f32x2 wv2; wv2.x = Wdt[(2*r)*256 + d]; wv2.y = Wdt[(2*r+1)*256 + d];
      wdt2[j][r] = wv2;
    }
    float a0 = -__expf(Alog[d*16]);
    chain = chain && (fabsf(a0 + 1.f) <= 1e-3f);
    #pragma unroll
    for (int s = 1; s < 16; ++s) {
      float as = -__expf(Alog[d*16 + s]);
      chain = chain && (fabsf(as - (float)(s+1)*a0) <= 1e-3f*(float)(s+1));
    }
  }

  const unsigned short* zp = (const unsigned short*)z + (size_t)n*NT*256 + dbase;
  unsigned short*       up = (unsigned short*)xh + (size_t)n*NT*256 + dbase;

  if (chain) {
    f32x2 h2[2][8];
    #pragma unroll
    for (int j = 0; j < 2; ++j)
      #pragma unroll
      for (int s = 0; s < 8; ++s) { h2[j][s].x = 0.f; h2[j][s].y = 0.f; }

    ushort2 ucur = *(const ushort2*)up;
    ushort2 zcur = *(const ushort2*)zp;
    f32x4 dA = *(const f32x4*)&sd[0][0];
    f32x4 dB = *(const f32x4*)&sd[0][4];

    for (int t = 0; t < NT; ++t) {
      const f32x4 Bv0 = *(const f32x4*)&sd[t][8];
      const f32x4 Bv1 = *(const f32x4*)&sd[t][12];
      const f32x4 Bv2 = *(const f32x4*)&sd[t][16];
      const f32x4 Bv3 = *(const f32x4*)&sd[t][20];
      const f32x4 Cv0 = *(const f32x4*)&sd[t][24];
      const f32x4 Cv1 = *(const f32x4*)&sd[t][28];
      const f32x4 Cv2 = *(const f32x4*)&sd[t][32];
      const f32x4 Cv3 = *(const f32x4*)&sd[t][36];
      const f32x4 dAn = *(const f32x4*)&sd[t+1][0];
      const f32x4 dBn = *(const f32x4*)&sd[t+1][4];
      // prefetch t+1 (unconditional; tail pads make last-row overrun safe)
      ushort2 unx = *(const ushort2*)(up + 256);
      ushort2 znx = *(const ushort2*)(zp + 256);

      float us[2] = { bs2f(ucur.x), bs2f(ucur.y) };
      float zs[2] = { bs2f(zcur.x), bs2f(zcur.y) };
      float yo[2];
      #pragma unroll
      for (int j = 0; j < 2; ++j) {
        f32x2 a2; a2.x = bd[j]; a2.y = 0.f;
        a2 += lo2(dA)*wdt2[j][0];
        a2 += hi2(dA)*wdt2[j][1];
        a2 += lo2(dB)*wdt2[j][2];
        a2 += hi2(dB)*wdt2[j][3];
        float dtv = a2.x + a2.y;
        // E = sigmoid(-dtv), delta = softplus(dtv)
        float q  = __expf(-fabsf(dtv));
        float r1 = __builtin_amdgcn_rcpf(1.f + q);
        float E  = dtv > 0.f ? q*r1 : r1;
        float delta = fmaxf(dtv, 0.f) - __logf(r1);
        float E2v = E*E;
        f32x2 ee; ee.x = E2v; ee.y = E2v;
        f32x2 pcur; pcur.x = E; pcur.y = E2v;
        float du = delta*us[j];
        f32x2 du2; du2.x = du; du2.y = du;
        f32x2 y2; y2.x = 0.f; y2.y = 0.f;

        h2[j][0] = h2[j][0]*pcur + du2*lo2(Bv0);  y2 += h2[j][0]*lo2(Cv0);  pcur = pcur*ee;
        h2[j][1] = h2[j][1]*pcur + du2*hi2(Bv0);  y2 += h2[j][1]*hi2(Cv0);  pcur = pcur*ee;
        h2[j][2] = h2[j][2]*pcur + du2*lo2(Bv1);  y2 += h2[j][2]*lo2(Cv1);  pcur = pcur*ee;
        h2[j][3] = h2[j][3]*pcur + du2*hi2(Bv1);  y2 += h2[j][3]*hi2(Cv1);  pcur = pcur*ee;
        h2[j][4] = h2[j][4]*pcur + du2*lo2(Bv2);  y2 += h2[j][4]*lo2(Cv2);  pcur = pcur*ee;
        h2[j][5] = h2[j][5]*pcur + du2*hi2(Bv2);  y2 += h2[j][5]*hi2(Cv2);  pcur = pcur*ee;
        h2[j][6] = h2[j][6]*pcur + du2*lo2(Bv3);  y2 += h2[j][6]*lo2(Cv3);  pcur = pcur*ee;
        h2[j][7] = h2[j][7]*pcur + du2*hi2(Bv3);  y2 += h2[j][7]*hi2(Cv3);

        float yt = y2.x + y2.y;
        yo[j] = (yt + us[j]*dp2[j]) * zs[j];
      }
      ushort2 ov; ov.x = f2bs(yo[0]); ov.y = f2bs(yo[1]);
      *(ushort2*)up = ov;
      up += 256; zp += 256;
      dA = dAn; dB = dBn;
      ucur = unx; zcur = znx;
    }
  } else {
    // correctness fallback: 2 sequential passes, one channel per pass
    for (int j = 0; j < 2; ++j) {
      int d = dbase + j;
      float wdt[8];
      #pragma unroll
      for (int r = 0; r < 8; ++r) wdt[r] = Wdt[r*256 + d];
      float Av[16];
      #pragma unroll
      for (int s = 0; s < 16; ++s) Av[s] = -__expf(Alog[d*16 + s]);
      float h[16];
      #pragma unroll
      for (int s = 0; s < 16; ++s) h[s] = 0.f;
      const unsigned short* zq = (const unsigned short*)z + (size_t)n*NT*256 + d;
      unsigned short*       uq = (unsigned short*)xh + (size_t)n*NT*256 + d;
      for (int t = 0; t < NT; ++t) {
        float dtv = bd[j];
        #pragma unroll
        for (int r = 0; r < 8; ++r) dtv += sd[t][r]*wdt[r];
        float delta = softplusf(dtv);
        float ut = bs2f(uq[0]);
        float du = delta*ut;
        float yt = 0.f;
        #pragma unroll
        for (int s = 0; s < 16; ++s) {
          float e = __expf(delta*Av[s]);
          h[s] = h[s]*e + du*sd[t][8+s];
          yt  += h[s]*sd[t][24+s];
        }
        float y = (yt + ut*dp2[j]) * bs2f(zq[0]);
        uq[0] = f2bs(y);
        uq += 256; zq += 256;
      }
    }
  }
}

// ---------------------------------------------------------------------------
// 7) final rmsnorm + flat head. One wave per (n,t) row; u is bf16.
__global__ __launch_bounds__(256) void k_head(const unsigned short* __restrict__ u,
                       const float* __restrict__ fnw,
                       const float* __restrict__ hw, const float* __restrict__ hfb,
                       float* __restrict__ y1)
{
  int n = blockIdx.x;
  int w = threadIdx.x >> 6, lane = threadIdx.x & 63;
  const float2 fw = *(const float2*)&fnw[lane*2];
  float acc = 0.f;
  for (int t = w; t < NT; t += 4) {
    const ushort2 vb = *(const ushort2*)&u[((size_t)n*NT + t)*NDM + lane*2];
    float vx = bs2f(vb.x), vy = bs2f(vb.y);
    const float2 hv = *(const float2*)&hw[t*NDM + lane*2];
    float ss = vx*vx + vy*vy;
    #pragma unroll
    for (int o = 32; o >= 1; o >>= 1) ss += __shfl_xor(ss, o);
    float sc = rsqrtf(ss*(1.f/128.f) + 1e-5f);
    acc += (vx*fw.x*hv.x + vy*fw.y*hv.y)*sc;
  }
  #pragma unroll
  for (int o = 32; o >= 1; o >>= 1) acc += __shfl_xor(acc, o);
  __shared__ float ws[4];
  if (lane == 0) ws[w] = acc;
  __syncthreads();
  if (threadIdx.x == 0) y1[n] = ws[0] + ws[1] + ws[2] + ws[3] + hfb[0];
}

// ---------------------------------------------------------------------------
// 8) out[b,c] = sum_p y1[b*64+p]*Wh[p,c] + bh[c].
__global__ __launch_bounds__(64) void k_final(const float* __restrict__ y1,
                        const float* __restrict__ Wh,
                        const float* __restrict__ bh, float* __restrict__ out)
{
  int t = threadIdx.x;
  int b = t >> 1, c = t & 1;
  float acc = bh[c];
  #pragma unroll 8
  for (int p = 0; p < 64; ++p) acc += y1[b*64 + p]*Wh[p*2 + c];
  out[b*2 + c] = acc;
}

// ---------------------------------------------------------------------------
extern "C" void kernel_launch(void* const* d_in, const int* in_sizes, int n_in,
                              void* d_out, int out_size, void* d_ws, size_t ws_size,
                              hipStream_t stream)
{
  const float* x    = (const float*)d_in[0];
  const float* Wp   = (const float*)d_in[1];
  const float* bp   = (const float*)d_in[2];
  const float* We   = (const float*)d_in[3];
  const float* be   = (const float*)d_in[4];
  const float* nrm  = (const float*)d_in[5];
  const float* Wi   = (const float*)d_in[6];
  const float* cw   = (const float*)d_in[7];
  const float* cb   = (const float*)d_in[8];
  const float* Wx   = (const float*)d_in[9];
  const float* Wdt  = (const float*)d_in[10];
  const float* bdt  = (const float*)d_in[11];
  const float* Alog = (const float*)d_in[12];
  const float* Dpp  = (const float*)d_in[13];
  const float* Wo   = (const float*)d_in[14];
  const float* fnw  = (const float*)d_in[15];
  const float* hw   = (const float*)d_in[16];
  const float* hfb  = (const float*)d_in[17];
  const float* Wh   = (const float*)d_in[18];
  const float* bh   = (const float*)d_in[19];

  // ---- workspace layout + adaptive chunking (u bf16; xh/z have 1KB pads) ----
  const size_t wt_per_l = (size_t)512*128 + 128*256 + 64*256;   // shorts
  const size_t fixed_b = (size_t)NROW*NDM*2 + (size_t)NSEQ*NK*4 + NSEQ*4
                       + wt_per_l*2*NNL + 16384;
  const size_t per_seq = (size_t)NT*256*2*2 + (size_t)NT*40*4;
  int ch_seq = NSEQ;
  while (ch_seq > 128 && fixed_b + (size_t)ch_seq*per_seq + 4096 > ws_size)
    ch_seq >>= 1;
  const int nchunk  = NSEQ / ch_seq;
  const int ch_rows = ch_seq * NT;
  fprintf(stderr, "[mamba] ws_size=%zu ch_seq=%d nchunk=%d\n", ws_size, ch_seq, nchunk);

  char* pw = (char*)d_ws;
  unsigned short* u = (unsigned short*)pw; pw += (size_t)NROW*NDM*2;
  float* hp   = (float*)pw; pw += (size_t)NSEQ*NK*4;
  float* y1   = (float*)pw; pw += (size_t)NSEQ*4;
  unsigned short* WiT = (unsigned short*)pw; pw += (size_t)NNL*512*128*2;
  unsigned short* WoT = (unsigned short*)pw; pw += (size_t)NNL*128*256*2;
  unsigned short* WxT = (unsigned short*)pw; pw += (size_t)NNL*64*256*2;
  float* dbl  = (float*)pw; pw += (size_t)ch_rows*40*4;
  bf16*  xh   = (bf16*)pw;  pw += (size_t)ch_rows*256*2 + 1024;  // +1KB pad (scan prefetch)
  bf16*  z    = (bf16*)pw;  pw += (size_t)ch_rows*256*2 + 1024;  // +1KB pad

  k_tw_all<<<3*704, 256, 0, stream>>>(Wi, Wo, Wx, WiT, WoT, WxT);
  k_proj <<<NB*64,   64, 0, stream>>>(x, Wp, bp, hp);
  k_embed<<<NROW/64, 256, 0, stream>>>(hp, We, be, u);

  for (int l = 0; l < NNL; ++l) {
    const float* nw_l  = nrm  + (size_t)l*NDM;
    const float* cw_l  = cw   + (size_t)l*NDI*4;
    const float* cb_l  = cb   + (size_t)l*NDI;
    const float* Wdt_l = Wdt  + (size_t)l*8*NDI;
    const float* bdt_l = bdt  + (size_t)l*NDI;
    const float* Al_l  = Alog + (size_t)l*NDI*16;
    const float* Dp_l  = Dpp  + (size_t)l*NDI;
    const unsigned short* WiT_l = WiT + (size_t)l*512*128;
    const unsigned short* WoT_l = WoT + (size_t)l*128*256;
    const unsigned short* WxT_l = WxT + (size_t)l*64*256;

    for (int c = 0; c < nchunk; ++c) {
      unsigned short* u_c = u + (size_t)c*ch_rows*NDM;
      k_inproj<<<ch_rows/64, 256, 0, stream>>>(
          u_c, WiT_l, (unsigned short*)xh, (unsigned short*)z, nw_l);
      k_conv<<<ch_seq, 256, 0, stream>>>(xh, cw_l, cb_l);
      k_mgemm<1,256,64><<<ch_rows/64, 256, 0, stream>>>(xh, WxT_l, dbl);
      k_scan<<<ch_seq, 128, 0, stream>>>(dbl, z, xh, Wdt_l, bdt_l, Al_l, Dp_l);
      k_mgemm<2,256,128><<<ch_rows/64, 256, 0, stream>>>(xh, WoT_l, u_c);
    }
  }

  k_head <<<NSEQ, 256, 0, stream>>>(u, fnw, hw, hfb, y1);
  k_final<<<1, 64, 0, stream>>>(y1, Wh, bh, (float*)d_out);
}

// Round 16
// 681.307 us; speedup vs baseline: 1.0886x; 1.0886x over previous
//
#include <hip/hip_runtime.h>
#include <hip/hip_bf16.h>
#include <cstdio>

typedef __hip_bfloat16 bf16;
typedef __attribute__((ext_vector_type(8))) short short8;   // 8 bf16 = 4 VGPR
typedef __attribute__((ext_vector_type(4))) short short4v;
typedef __attribute__((ext_vector_type(4))) float f32x4;
typedef __attribute__((ext_vector_type(2))) float f32x2;

#define NB    32
#define NK    256
#define NDIN  512
#define NPROJ 64
#define NDM   128
#define NNL   3
#define NT    63
#define NDI   256
#define NSEQ  2048            // NB*NPROJ
#define NROW  (NSEQ*NT)       // 129024
#define LDP   136             // LDS K-stride in shorts (17 * 16B)

static __device__ __forceinline__ float b2f(bf16 v){ return __bfloat162float(v); }
static __device__ __forceinline__ bf16  f2b(float v){ return __float2bfloat16(v); }
static __device__ __forceinline__ unsigned short f2bs(float v){   // RNE f32->bf16 bits
  unsigned int u = __float_as_uint(v);
  return (unsigned short)((u + 0x7FFFu + ((u >> 16) & 1u)) >> 16);
}
static __device__ __forceinline__ float bs2f(unsigned short b){   // bf16 bits -> f32
  return __uint_as_float(((unsigned int)b) << 16);
}
static __device__ __forceinline__ f32x2 lo2(f32x4 v){ f32x2 r; r.x = v.x; r.y = v.y; return r; }
static __device__ __forceinline__ f32x2 hi2(f32x4 v){ f32x2 r; r.x = v.z; r.y = v.w; return r; }
// silu via v_rcp (1 slot) instead of IEEE div (~9 slots)
static __device__ __forceinline__ float siluf(float x){
  return x * __builtin_amdgcn_rcpf(1.f + __expf(-x));
}
static __device__ __forceinline__ float softplusf(float x){
  float e = __expf(-fabsf(x));
  return fmaxf(x, 0.f) + __logf(1.f + e);
}

// ---------------------------------------------------------------------------
// 0) all-layer weight pre-transpose to K-major bf16 (one dispatch).
//    blocks [0, 3*704): per-layer Wi/Wo/Wx. blocks [3*704, 3*704+64): Wp.
__global__ __launch_bounds__(256) void k_tw_all(
    const float* __restrict__ Wi, const float* __restrict__ Wo,
    const float* __restrict__ Wx, const float* __restrict__ Wp,
    unsigned short* __restrict__ WiT, unsigned short* __restrict__ WoT,
    unsigned short* __restrict__ WxT, unsigned short* __restrict__ WpT)
{
  int bx = blockIdx.x;
  if (bx >= 3*704) {                 // Wp section: n = p, K=512, srcN=64
    int n = bx - 3*704;
    for (int k = threadIdx.x; k < 512; k += 256)
      WpT[(size_t)n*512 + k] = f2bs(Wp[(size_t)k*64 + n]);
    return;
  }
  int l = bx / 704, r = bx - l*704;
  const float* src; unsigned short* dst; int K, srcN, nvalid, n;
  if (r < 512)      { n = r;     src = Wi + (size_t)l*128*512; dst = WiT + (size_t)l*512*128; K=128; srcN=512; nvalid=512; }
  else if (r < 640) { n = r-512; src = Wo + (size_t)l*256*128; dst = WoT + (size_t)l*128*256; K=256; srcN=128; nvalid=128; }
  else              { n = r-640; src = Wx + (size_t)l*256*40;  dst = WxT + (size_t)l*64*256;  K=256; srcN=40;  nvalid=40; }
  for (int k = threadIdx.x; k < K; k += 256) {
    float v = (n < nvalid) ? src[(size_t)k*srcN + n] : 0.f;
    dst[(size_t)n*K + k] = f2bs(v);
  }
}

// ---------------------------------------------------------------------------
// 1) MFMA proj: hp[(b*64+p)*256 + k] = x[b,k,:].Wp[:,p] + bp[p].
//    M=8192 flat rows (b,k), N=64, K=512. block = 64 rows (one b, 64 k).
//    Epilogue: lane's 4 acc rows = 4 consecutive k -> float4 store.
__global__ __launch_bounds__(256) void k_projm(
    const float* __restrict__ x, const unsigned short* __restrict__ WpT,
    const float* __restrict__ bp, float* __restrict__ hp)
{
  __shared__ short As[64*LDP];
  __shared__ short Bs[64*LDP];
  const int tid = threadIdx.x;
  const int b   = blockIdx.x >> 2;
  const int kq  = blockIdx.x & 3;
  const int r0  = b*NK + kq*64;      // flat row base in x
  const int w    = tid >> 6;
  const int lane = tid & 63;
  const int l16  = lane & 15;
  const int quad = lane >> 4;
  const int WM   = (w >> 1) * 32;
  const int WN   = (w & 1) * 32;

  f32x4 acc[2][2] = {};
  for (int kc = 0; kc < 512; kc += 128) {
    if (kc) __syncthreads();
    #pragma unroll
    for (int j = 0; j < 4; ++j) {
      int c = tid + j*256;
      int row = c >> 4, k8 = (c & 15) << 3;
      const float* src = x + (size_t)(r0+row)*512 + kc + k8;
      float4 v0 = *(const float4*)src;
      float4 v1 = *(const float4*)(src + 4);
      short8 o;
      o[0]=(short)f2bs(v0.x); o[1]=(short)f2bs(v0.y); o[2]=(short)f2bs(v0.z); o[3]=(short)f2bs(v0.w);
      o[4]=(short)f2bs(v1.x); o[5]=(short)f2bs(v1.y); o[6]=(short)f2bs(v1.z); o[7]=(short)f2bs(v1.w);
      *(short8*)&As[row*LDP + k8] = o;
    }
    #pragma unroll
    for (int j = 0; j < 4; ++j) {
      int c = tid + j*256;
      int n = c >> 4, k8 = (c & 15) << 3;
      *(short8*)&Bs[n*LDP + k8] = *(const short8*)&WpT[(size_t)n*512 + kc + k8];
    }
    __syncthreads();
    #pragma unroll
    for (int ks = 0; ks < 4; ++ks) {
      short8 a[2], bb[2];
      #pragma unroll
      for (int i = 0; i < 2; ++i)
        a[i] = *(const short8*)&As[(WM + i*16 + l16)*LDP + ks*32 + quad*8];
      #pragma unroll
      for (int j = 0; j < 2; ++j)
        bb[j] = *(const short8*)&Bs[(WN + j*16 + l16)*LDP + ks*32 + quad*8];
      #pragma unroll
      for (int i = 0; i < 2; ++i)
        #pragma unroll
        for (int j = 0; j < 2; ++j)
          acc[i][j] = __builtin_amdgcn_mfma_f32_16x16x32_bf16(a[i], bb[j], acc[i][j], 0, 0, 0);
    }
  }
  #pragma unroll
  for (int j = 0; j < 2; ++j) {
    int col = WN + j*16 + l16;                 // p
    float bias = bp[col];
    #pragma unroll
    for (int i = 0; i < 2; ++i) {
      float4 o;
      o.x = acc[i][j][0] + bias; o.y = acc[i][j][1] + bias;
      o.z = acc[i][j][2] + bias; o.w = acc[i][j][3] + bias;
      *(float4*)&hp[(size_t)(b*64 + col)*256 + kq*64 + WM + i*16 + quad*4] = o;
    }
  }
}

// ---------------------------------------------------------------------------
// 2) u[n,t,m] (bf16) = sum_j hp[n][t*4+j] * We[j][m] + be[m]
__global__ __launch_bounds__(256, 4) void k_embed(const float* __restrict__ hp,
                        const float* __restrict__ We,
                        const float* __restrict__ be, unsigned short* __restrict__ u)
{
  __shared__ float sWe[8][NDM];
  __shared__ float sbe[NDM];
  for (int e = threadIdx.x; e < 8*NDM; e += 256) sWe[e >> 7][e & 127] = We[e];
  if (threadIdx.x < NDM) sbe[threadIdx.x] = be[threadIdx.x];
  __syncthreads();
  int r = blockIdx.x*64 + (threadIdx.x >> 2);
  int strip = (threadIdx.x & 3) * 32;
  int n = r / NT, t = r - n*NT;
  const float* hr = hp + (size_t)n*NK + t*4;
  float h[8];
  #pragma unroll
  for (int j = 0; j < 8; ++j) h[j] = hr[j];
  float acc[32];
  #pragma unroll
  for (int c = 0; c < 32; ++c) acc[c] = sbe[strip + c];
  #pragma unroll
  for (int j = 0; j < 8; ++j)
    #pragma unroll
    for (int c = 0; c < 32; ++c)
      acc[c] += h[j] * sWe[j][strip + c];
  unsigned short* dst = u + (size_t)r*NDM + strip;
  #pragma unroll
  for (int g = 0; g < 4; ++g) {
    short8 o;
    #pragma unroll
    for (int i = 0; i < 8; ++i) o[i] = (short)f2bs(acc[g*8 + i]);
    *(short8*)&dst[g*8] = o;
  }
}

// ---------------------------------------------------------------------------
// 3) in_proj + fused rmsnorm. A staged once; loop 4 B-tiles in-kernel.
//    z output stored PRE-GATED: zb = silu(zacc).
__global__ __launch_bounds__(256) void k_inproj(
    const unsigned short* __restrict__ ub, const unsigned short* __restrict__ WT,
    unsigned short* __restrict__ xh, unsigned short* __restrict__ zb,
    const float* __restrict__ nw)
{
  __shared__ short As[64*LDP];
  __shared__ short Bs[128*LDP];
  const int tid  = threadIdx.x;
  const int r0   = blockIdx.x * 64;
  const int w    = tid >> 6;
  const int lane = tid & 63;
  const int l16  = lane & 15;
  const int quad = lane >> 4;
  const int WM   = (w >> 1) * 32;
  const int WN   = (w & 1) * 64;

  #pragma unroll
  for (int j = 0; j < 4; ++j) {
    int c = tid + j*256;
    int row = c >> 4, k8 = (c & 15) << 3;
    short8 vb = *(const short8*)&ub[(size_t)(r0+row)*128 + k8];
    float f[8];
    #pragma unroll
    for (int i = 0; i < 8; ++i) f[i] = bs2f((unsigned short)vb[i]);
    float ss = 0.f;
    #pragma unroll
    for (int i = 0; i < 8; ++i) ss += f[i]*f[i];
    #pragma unroll
    for (int m = 8; m >= 1; m >>= 1) ss += __shfl_xor(ss, m, 16);
    float sc = rsqrtf(ss*(1.f/128.f) + 1e-5f);
    const float4 nw0 = *(const float4*)&nw[k8];
    const float4 nw1 = *(const float4*)&nw[k8+4];
    short8 o;
    o[0] = (short)f2bs(f[0]*sc*nw0.x); o[1] = (short)f2bs(f[1]*sc*nw0.y);
    o[2] = (short)f2bs(f[2]*sc*nw0.z); o[3] = (short)f2bs(f[3]*sc*nw0.w);
    o[4] = (short)f2bs(f[4]*sc*nw1.x); o[5] = (short)f2bs(f[5]*sc*nw1.y);
    o[6] = (short)f2bs(f[6]*sc*nw1.z); o[7] = (short)f2bs(f[7]*sc*nw1.w);
    *(short8*)&As[row*LDP + k8] = o;
  }

  for (int ny = 0; ny < 4; ++ny) {
    if (ny) __syncthreads();
    #pragma unroll
    for (int j = 0; j < 8; ++j) {
      int c = tid + j*256;
      int n = c >> 4, k8 = (c & 15) << 3;
      *(short8*)&Bs[n*LDP + k8] =
          *(const short8*)&WT[(size_t)(ny*128 + n)*128 + k8];
    }
    __syncthreads();

    f32x4 acc[2][4] = {};
    #pragma unroll
    for (int ks = 0; ks < 4; ++ks) {
      short8 a[2], b[4];
      #pragma unroll
      for (int i = 0; i < 2; ++i)
        a[i] = *(const short8*)&As[(WM + i*16 + l16)*LDP + ks*32 + quad*8];
      #pragma unroll
      for (int j = 0; j < 4; ++j)
        b[j] = *(const short8*)&Bs[(WN + j*16 + l16)*LDP + ks*32 + quad*8];
      #pragma unroll
      for (int i = 0; i < 2; ++i)
        #pragma unroll
        for (int j = 0; j < 4; ++j)
          acc[i][j] = __builtin_amdgcn_mfma_f32_16x16x32_bf16(a[i], b[j], acc[i][j], 0, 0, 0);
    }
    #pragma unroll
    for (int i = 0; i < 2; ++i) {
      #pragma unroll
      for (int j = 0; j < 4; ++j) {
        #pragma unroll
        for (int rr = 0; rr < 4; ++rr) {
          int row = r0 + WM + i*16 + quad*4 + rr;
          int col = ny*128 + WN + j*16 + l16;
          float v = acc[i][j][rr];
          if (col < 256) xh[(size_t)row*256 + col]       = f2bs(v);
          else           zb[(size_t)row*256 + col - 256] = f2bs(siluf(v));
        }
      }
    }
  }
}

// ---------------------------------------------------------------------------
// 4) MFMA GEMM (x_proj / out_proj).
template<int MODE, int KTOT, int BN>
__global__ __launch_bounds__(256) void
k_mgemm(const void* __restrict__ Aptr, const unsigned short* __restrict__ WT,
        void* __restrict__ Cptr)
{
  constexpr int MJ = BN/32;
  __shared__ short As[64*LDP];
  __shared__ short Bs[BN*LDP];

  const int tid  = threadIdx.x;
  const int r0   = blockIdx.x * 64;
  const int w    = tid >> 6;
  const int lane = tid & 63;
  const int l16  = lane & 15;
  const int quad = lane >> 4;
  const int WM   = (w >> 1) * 32;
  const int WN   = (w & 1) * (BN/2);

  f32x4 acc[2][MJ] = {};

  for (int kc = 0; kc < KTOT; kc += 128) {
    #pragma unroll
    for (int j = 0; j < 4; ++j) {
      int c   = tid + j*256;
      int row = c >> 4, k8 = (c & 15) << 3;
      short8 v = *(const short8*)((const unsigned short*)Aptr
                                  + (size_t)(r0+row)*256 + kc + k8);
      *(short8*)&As[row*LDP + k8] = v;
    }
    #pragma unroll
    for (int j = 0; j < BN/16; ++j) {
      int c  = tid + j*256;
      int n  = c >> 4, k8 = (c & 15) << 3;
      short8 v = *(const short8*)(WT + (size_t)n*KTOT + kc + k8);
      *(short8*)&Bs[n*LDP + k8] = v;
    }
    __syncthreads();

    #pragma unroll
    for (int ks = 0; ks < 4; ++ks) {
      short8 a[2], b[MJ];
      #pragma unroll
      for (int i = 0; i < 2; ++i)
        a[i] = *(const short8*)&As[(WM + i*16 + l16)*LDP + ks*32 + quad*8];
      #pragma unroll
      for (int j = 0; j < MJ; ++j)
        b[j] = *(const short8*)&Bs[(WN + j*16 + l16)*LDP + ks*32 + quad*8];
      #pragma unroll
      for (int i = 0; i < 2; ++i)
        #pragma unroll
        for (int j = 0; j < MJ; ++j)
          acc[i][j] = __builtin_amdgcn_mfma_f32_16x16x32_bf16(a[i], b[j], acc[i][j], 0, 0, 0);
    }
    __syncthreads();
  }

  #pragma unroll
  for (int i = 0; i < 2; ++i) {
    #pragma unroll
    for (int j = 0; j < MJ; ++j) {
      #pragma unroll
      for (int rr = 0; rr < 4; ++rr) {
        int row = r0 + WM + i*16 + quad*4 + rr;
        int col = WN + j*16 + l16;
        float v = acc[i][j][rr];
        if (MODE == 1) {
          if (col < 40) ((float*)Cptr)[(size_t)row*40 + col] = v;
        } else {
          unsigned short* p = (unsigned short*)Cptr + (size_t)row*128 + col;
          *p = f2bs(bs2f(*p) + v);
        }
      }
    }
  }
}

// ---------------------------------------------------------------------------
// 5) depthwise causal conv(4) + bias + silu, IN PLACE on xh (stride 256).
__global__ __launch_bounds__(256, 8) void k_conv(bf16* __restrict__ xh,
                       const float* __restrict__ cw, const float* __restrict__ cb)
{
  int n = blockIdx.x, d = threadIdx.x;
  float w0 = cw[d*4+0], w1 = cw[d*4+1];
  float w2 = cw[d*4+2], w3 = cw[d*4+3];
  float bias = cb[d];
  float xm3 = 0.f, xm2 = 0.f, xm1 = 0.f;
  bf16* ptr = xh + (size_t)n*NT*256 + d;
  for (int t = 0; t < NT; ++t) {
    float xt = b2f(ptr[0]);
    float a  = bias + w0*xm3 + w1*xm2 + w2*xm1 + w3*xt;
    ptr[0] = f2b(siluf(a));
    ptr += 256;
    xm3 = xm2; xm2 = xm1; xm1 = xt;
  }
}

// ---------------------------------------------------------------------------
// 6) fused dt_proj + softplus + selective scan + skip + gating (z pre-silu'd).
//    W=2 (128 thr), f32x2 packed math, dt-row + u/z prefetch. (R13 verbatim —
//    best-measured scan config: d_j = lane + 128*wave + 64*j.)
__global__ __launch_bounds__(128, 4) void k_scan(const float* __restrict__ dbl,
                       const bf16* __restrict__ z, bf16* __restrict__ xh,
                       const float* __restrict__ Wdt, const float* __restrict__ bdt,
                       const float* __restrict__ Alog, const float* __restrict__ Dpp)
{
  int n = blockIdx.x;
  int tid = threadIdx.x;
  int lane = tid & 63, wv = tid >> 6;
  __shared__ __align__(16) float sd[NT+1][40];    // dt(8) | B(16) | C(16); +1 pad row
  for (int i = tid; i < NT*40; i += 128)
    sd[i/40][i%40] = dbl[(size_t)n*NT*40 + i];
  if (tid < 40) sd[NT][tid] = 0.f;
  __syncthreads();

  const int dbase = lane + 128*wv;
  float bd[2], dp2[2];
  f32x2 wdt2[2][4];
  bool chain = true;
  #pragma unroll
  for (int j = 0; j < 2; ++j) {
    int d = dbase + 64*j;
    bd[j]  = bdt[d];
    dp2[j] = Dpp[d];
    #pragma unroll
    for (int r = 0; r < 4; ++r) {
      f32x2 wv2; wv2.x = Wdt[(2*r)*256 + d]; wv2.y = Wdt[(2*r+1)*256 + d];
      wdt2[j][r] = wv2;
    }
    float a0 = -__expf(Alog[d*16]);
    chain = chain && (fabsf(a0 + 1.f) <= 1e-3f);
    #pragma unroll
    for (int s = 1; s < 16; ++s) {
      float as = -__expf(Alog[d*16 + s]);
      chain = chain && (fabsf(as - (float)(s+1)*a0) <= 1e-3f*(float)(s+1));
    }
  }

  const unsigned short* zp = (const unsigned short*)z + (size_t)n*NT*256 + dbase;
  unsigned short*       up = (unsigned short*)xh + (size_t)n*NT*256 + dbase;

  if (chain) {
    f32x2 h2[2][8];
    #pragma unroll
    for (int j = 0; j < 2; ++j)
      #pragma unroll
      for (int s = 0; s < 8; ++s) { h2[j][s].x = 0.f; h2[j][s].y = 0.f; }

    float us[2], zs[2];
    #pragma unroll
    for (int j = 0; j < 2; ++j) { us[j] = bs2f(up[64*j]); zs[j] = bs2f(zp[64*j]); }
    f32x4 dA = *(const f32x4*)&sd[0][0];
    f32x4 dB = *(const f32x4*)&sd[0][4];

    for (int t = 0; t < NT; ++t) {
      const f32x4 Bv0 = *(const f32x4*)&sd[t][8];
      const f32x4 Bv1 = *(const f32x4*)&sd[t][12];
      const f32x4 Bv2 = *(const f32x4*)&sd[t][16];
      const f32x4 Bv3 = *(const f32x4*)&sd[t][20];
      const f32x4 Cv0 = *(const f32x4*)&sd[t][24];
      const f32x4 Cv1 = *(const f32x4*)&sd[t][28];
      const f32x4 Cv2 = *(const f32x4*)&sd[t][32];
      const f32x4 Cv3 = *(const f32x4*)&sd[t][36];
      const f32x4 dAn = *(const f32x4*)&sd[t+1][0];
      const f32x4 dBn = *(const f32x4*)&sd[t+1][4];
      float un[2], zn[2];
      #pragma unroll
      for (int j = 0; j < 2; ++j) { un[j] = bs2f(up[256 + 64*j]); zn[j] = bs2f(zp[256 + 64*j]); }

      #pragma unroll
      for (int j = 0; j < 2; ++j) {
        f32x2 a2; a2.x = bd[j]; a2.y = 0.f;
        a2 += lo2(dA)*wdt2[j][0];
        a2 += hi2(dA)*wdt2[j][1];
        a2 += lo2(dB)*wdt2[j][2];
        a2 += hi2(dB)*wdt2[j][3];
        float dtv = a2.x + a2.y;
        float q  = __expf(-fabsf(dtv));
        float r1 = __builtin_amdgcn_rcpf(1.f + q);
        float E  = dtv > 0.f ? q*r1 : r1;
        float delta = fmaxf(dtv, 0.f) - __logf(r1);
        float E2v = E*E;
        f32x2 ee; ee.x = E2v; ee.y = E2v;
        f32x2 pcur; pcur.x = E; pcur.y = E2v;
        float du = delta*us[j];
        f32x2 du2; du2.x = du; du2.y = du;
        f32x2 y2; y2.x = 0.f; y2.y = 0.f;

        h2[j][0] = h2[j][0]*pcur + du2*lo2(Bv0);  y2 += h2[j][0]*lo2(Cv0);  pcur = pcur*ee;
        h2[j][1] = h2[j][1]*pcur + du2*hi2(Bv0);  y2 += h2[j][1]*hi2(Cv0);  pcur = pcur*ee;
        h2[j][2] = h2[j][2]*pcur + du2*lo2(Bv1);  y2 += h2[j][2]*lo2(Cv1);  pcur = pcur*ee;
        h2[j][3] = h2[j][3]*pcur + du2*hi2(Bv1);  y2 += h2[j][3]*hi2(Cv1);  pcur = pcur*ee;
        h2[j][4] = h2[j][4]*pcur + du2*lo2(Bv2);  y2 += h2[j][4]*lo2(Cv2);  pcur = pcur*ee;
        h2[j][5] = h2[j][5]*pcur + du2*hi2(Bv2);  y2 += h2[j][5]*hi2(Cv2);  pcur = pcur*ee;
        h2[j][6] = h2[j][6]*pcur + du2*lo2(Bv3);  y2 += h2[j][6]*lo2(Cv3);  pcur = pcur*ee;
        h2[j][7] = h2[j][7]*pcur + du2*hi2(Bv3);  y2 += h2[j][7]*hi2(Cv3);

        float yt = y2.x + y2.y;
        float yv = (yt + us[j]*dp2[j]) * zs[j];
        up[64*j] = f2bs(yv);
      }
      up += 256; zp += 256;
      dA = dAn; dB = dBn;
      us[0] = un[0]; us[1] = un[1]; zs[0] = zn[0]; zs[1] = zn[1];
    }
  } else {
    for (int j = 0; j < 2; ++j) {
      int d = dbase + 64*j;
      float wdt[8];
      #pragma unroll
      for (int r = 0; r < 8; ++r) wdt[r] = Wdt[r*256 + d];
      float Av[16];
      #pragma unroll
      for (int s = 0; s < 16; ++s) Av[s] = -__expf(Alog[d*16 + s]);
      float h[16];
      #pragma unroll
      for (int s = 0; s < 16; ++s) h[s] = 0.f;
      const unsigned short* zq = (const unsigned short*)z + (size_t)n*NT*256 + d;
      unsigned short*       uq = (unsigned short*)xh + (size_t)n*NT*256 + d;
      for (int t = 0; t < NT; ++t) {
        float dtv = bd[j];
        #pragma unroll
        for (int r = 0; r < 8; ++r) dtv += sd[t][r]*wdt[r];
        float delta = softplusf(dtv);
        float ut = bs2f(uq[0]);
        float du = delta*ut;
        float yt = 0.f;
        #pragma unroll
        for (int s = 0; s < 16; ++s) {
          float e = __expf(delta*Av[s]);
          h[s] = h[s]*e + du*sd[t][8+s];
          yt  += h[s]*sd[t][24+s];
        }
        float y = (yt + ut*dp2[j]) * bs2f(zq[0]);
        uq[0] = f2bs(y);
        uq += 256; zq += 256;
      }
    }
  }
}

// ---------------------------------------------------------------------------
// 7) final rmsnorm + flat head. One wave per (n,t) row; u is bf16.
__global__ __launch_bounds__(256) void k_head(const unsigned short* __restrict__ u,
                       const float* __restrict__ fnw,
                       const float* __restrict__ hw, const float* __restrict__ hfb,
                       float* __restrict__ y1)
{
  int n = blockIdx.x;
  int w = threadIdx.x >> 6, lane = threadIdx.x & 63;
  const float2 fw = *(const float2*)&fnw[lane*2];
  float acc = 0.f;
  for (int t = w; t < NT; t += 4) {
    const ushort2 vb = *(const ushort2*)&u[((size_t)n*NT + t)*NDM + lane*2];
    float vx = bs2f(vb.x), vy = bs2f(vb.y);
    const float2 hv = *(const float2*)&hw[t*NDM + lane*2];
    float ss = vx*vx + vy*vy;
    #pragma unroll
    for (int o = 32; o >= 1; o >>= 1) ss += __shfl_xor(ss, o);
    float sc = rsqrtf(ss*(1.f/128.f) + 1e-5f);
    acc += (vx*fw.x*hv.x + vy*fw.y*hv.y)*sc;
  }
  #pragma unroll
  for (int o = 32; o >= 1; o >>= 1) acc += __shfl_xor(acc, o);
  __shared__ float ws[4];
  if (lane == 0) ws[w] = acc;
  __syncthreads();
  if (threadIdx.x == 0) y1[n] = ws[0] + ws[1] + ws[2] + ws[3] + hfb[0];
}

// ---------------------------------------------------------------------------
// 8) out[b,c] = sum_p y1[b*64+p]*Wh[p,c] + bh[c].
__global__ __launch_bounds__(64) void k_final(const float* __restrict__ y1,
                        const float* __restrict__ Wh,
                        const float* __restrict__ bh, float* __restrict__ out)
{
  int t = threadIdx.x;
  int b = t >> 1, c = t & 1;
  float acc = bh[c];
  #pragma unroll 8
  for (int p = 0; p < 64; ++p) acc += y1[b*64 + p]*Wh[p*2 + c];
  out[b*2 + c] = acc;
}

// ---------------------------------------------------------------------------
extern "C" void kernel_launch(void* const* d_in, const int* in_sizes, int n_in,
                              void* d_out, int out_size, void* d_ws, size_t ws_size,
                              hipStream_t stream)
{
  const float* x    = (const float*)d_in[0];
  const float* Wp   = (const float*)d_in[1];
  const float* bp   = (const float*)d_in[2];
  const float* We   = (const float*)d_in[3];
  const float* be   = (const float*)d_in[4];
  const float* nrm  = (const float*)d_in[5];
  const float* Wi   = (const float*)d_in[6];
  const float* cw   = (const float*)d_in[7];
  const float* cb   = (const float*)d_in[8];
  const float* Wx   = (const float*)d_in[9];
  const float* Wdt  = (const float*)d_in[10];
  const float* bdt  = (const float*)d_in[11];
  const float* Alog = (const float*)d_in[12];
  const float* Dpp  = (const float*)d_in[13];
  const float* Wo   = (const float*)d_in[14];
  const float* fnw  = (const float*)d_in[15];
  const float* hw   = (const float*)d_in[16];
  const float* hfb  = (const float*)d_in[17];
  const float* Wh   = (const float*)d_in[18];
  const float* bh   = (const float*)d_in[19];

  // ---- workspace layout + adaptive chunking (u bf16; xh/z have 1KB pads) ----
  const size_t wt_per_l = (size_t)512*128 + 128*256 + 64*256;   // shorts
  const size_t fixed_b = (size_t)NROW*NDM*2 + (size_t)NSEQ*NK*4 + NSEQ*4
                       + wt_per_l*2*NNL + 64*512*2 + 16384;
  const size_t per_seq = (size_t)NT*256*2*2 + (size_t)NT*40*4;
  int ch_seq = NSEQ;
  while (ch_seq > 128 && fixed_b + (size_t)ch_seq*per_seq + 4096 > ws_size)
    ch_seq >>= 1;
  const int nchunk  = NSEQ / ch_seq;
  const int ch_rows = ch_seq * NT;
  fprintf(stderr, "[mamba] ws_size=%zu ch_seq=%d nchunk=%d\n", ws_size, ch_seq, nchunk);

  char* pw = (char*)d_ws;
  unsigned short* u = (unsigned short*)pw; pw += (size_t)NROW*NDM*2;
  float* hp   = (float*)pw; pw += (size_t)NSEQ*NK*4;
  float* y1   = (float*)pw; pw += (size_t)NSEQ*4;
  unsigned short* WiT = (unsigned short*)pw; pw += (size_t)NNL*512*128*2;
  unsigned short* WoT = (unsigned short*)pw; pw += (size_t)NNL*128*256*2;
  unsigned short* WxT = (unsigned short*)pw; pw += (size_t)NNL*64*256*2;
  unsigned short* WpT = (unsigned short*)pw; pw += (size_t)64*512*2;
  float* dbl  = (float*)pw; pw += (size_t)ch_rows*40*4;
  bf16*  xh   = (bf16*)pw;  pw += (size_t)ch_rows*256*2 + 1024;  // +1KB pad (scan prefetch)
  bf16*  z    = (bf16*)pw;  pw += (size_t)ch_rows*256*2 + 1024;  // +1KB pad

  k_tw_all<<<3*704 + 64, 256, 0, stream>>>(Wi, Wo, Wx, Wp, WiT, WoT, WxT, WpT);
  k_projm<<<NB*4,   256, 0, stream>>>(x, WpT, bp, hp);
  k_embed<<<NROW/64, 256, 0, stream>>>(hp, We, be, u);

  for (int l = 0; l < NNL; ++l) {
    const float* nw_l  = nrm  + (size_t)l*NDM;
    const float* cw_l  = cw   + (size_t)l*NDI*4;
    const float* cb_l  = cb   + (size_t)l*NDI;
    const float* Wdt_l = Wdt  + (size_t)l*8*NDI;
    const float* bdt_l = bdt  + (size_t)l*NDI;
    const float* Al_l  = Alog + (size_t)l*NDI*16;
    const float* Dp_l  = Dpp  + (size_t)l*NDI;
    const unsigned short* WiT_l = WiT + (size_t)l*512*128;
    const unsigned short* WoT_l = WoT + (size_t)l*128*256;
    const unsigned short* WxT_l = WxT + (size_t)l*64*256;

    for (int c = 0; c < nchunk; ++c) {
      unsigned short* u_c = u + (size_t)c*ch_rows*NDM;
      k_inproj<<<ch_rows/64, 256, 0, stream>>>(
          u_c, WiT_l, (unsigned short*)xh, (unsigned short*)z, nw_l);
      k_conv<<<ch_seq, 256, 0, stream>>>(xh, cw_l, cb_l);
      k_mgemm<1,256,64><<<ch_rows/64, 256, 0, stream>>>(xh, WxT_l, dbl);
      k_scan<<<ch_seq, 128, 0, stream>>>(dbl, z, xh, Wdt_l, bdt_l, Al_l, Dp_l);
      k_mgemm<2,256,128><<<ch_rows/64, 256, 0, stream>>>(xh, WoT_l, u_c);
    }
  }

  k_head <<<NSEQ, 256, 0, stream>>>(u, fnw, hw, hfb, y1);
  k_final<<<1, 64, 0, stream>>>(y1, Wh, bh, (float*)d_out);
}